// Round 1
// baseline (245.144 us; speedup 1.0000x reference)
//
#include <hip/hip_runtime.h>

#define DIMK 128
#define EPSQ 1e-8f

typedef __bf16 bf16x8 __attribute__((ext_vector_type(8)));
typedef float  f32x4  __attribute__((ext_vector_type(4)));

// ---- helpers ---------------------------------------------------------------
__device__ inline unsigned short f32_to_bf16_rne(float f) {
    unsigned u = __float_as_uint(f);
    u += 0x7FFFu + ((u >> 16) & 1u);      // round-to-nearest-even
    return (unsigned short)(u >> 16);
}

// ---- kernel 1: target f32 -> bf16, plus t2 = ||t||^2 -----------------------
// one wave per row; lane handles 2 columns
__global__ void conv_target(const float* __restrict__ tgt,
                            unsigned short* __restrict__ tb,
                            float* __restrict__ t2, int n_pos) {
    int wave = threadIdx.x >> 6, lane = threadIdx.x & 63;
    int row = blockIdx.x * 4 + wave;
    if (row >= n_pos) return;
    float2 v = *(const float2*)(tgt + (size_t)row * DIMK + lane * 2);
    unsigned pk = (unsigned)f32_to_bf16_rne(v.x) |
                  ((unsigned)f32_to_bf16_rne(v.y) << 16);
    *(unsigned*)(tb + (size_t)row * DIMK + lane * 2) = pk;
    float s = v.x * v.x + v.y * v.y;
#pragma unroll
    for (int o = 1; o < 64; o <<= 1) s += __shfl_xor(s, o, 64);
    if (lane == 0) t2[row] = s;
}

// ---- kernel 2: segment counts -> per-position (t2, w) packed float2 --------
__global__ void seg_weights(const int* __restrict__ ids,
                            const int* __restrict__ nseg_p,
                            const float* __restrict__ t2,
                            float2* __restrict__ tw, int n_pos) {
    __shared__ int   cnt[256];
    __shared__ float w[256];
    int nseg = nseg_p[0];
    if (nseg > 256) nseg = 256;
    int t = threadIdx.x;
    if (t < nseg) cnt[t] = 0;
    __syncthreads();
    for (int p = t; p < n_pos; p += blockDim.x) atomicAdd(&cnt[ids[p]], 1);
    __syncthreads();
    if (t < nseg) w[t] = 1.0f / ((float)nseg * (float)max(cnt[t], 1));
    __syncthreads();
    for (int p = t; p < n_pos; p += blockDim.x) {
        float2 e; e.x = t2[p]; e.y = w[ids[p]];
        tw[p] = e;
    }
}

// ---- kernel 3: fused cross-GEMM + sqrt + weighted reduce -------------------
// block = 256 threads = 4 waves; wave owns 16 nodes; grid.y splits positions.
__global__ __launch_bounds__(256)
void l2dist_main(const float* __restrict__ pred,
                 const unsigned short* __restrict__ tb,   // bf16 bits
                 const float2* __restrict__ tw,
                 float* __restrict__ out,
                 int n_nodes, int n_pos) {
    int lane = threadIdx.x & 63;
    int wave = threadIdx.x >> 6;
    int col  = lane & 15;          // node within wave-tile / A-row (p within tile)
    int kb   = lane >> 4;          // k-block 0..3 (8 elements each within K=32)
    int n0   = blockIdx.x * 64 + wave * 16;
    int n    = n0 + col;
    int nc   = min(n, n_nodes - 1);

    // Build B fragments from pred row nc (fp32 -> bf16 in registers) + p2.
    bf16x8 bfrag[4];
    float p2 = 0.f;
    const float* pr = pred + (size_t)nc * DIMK + kb * 8;
#pragma unroll
    for (int kk = 0; kk < 4; ++kk) {
        f32x4 f0 = *(const f32x4*)(pr + kk * 32);
        f32x4 f1 = *(const f32x4*)(pr + kk * 32 + 4);
        union { unsigned short s[8]; bf16x8 v; } u;
#pragma unroll
        for (int j = 0; j < 4; ++j) {
            u.s[j]     = f32_to_bf16_rne(f0[j]);
            u.s[4 + j] = f32_to_bf16_rne(f1[j]);
            p2 += f0[j] * f0[j] + f1[j] * f1[j];
        }
        bfrag[kk] = u.v;
    }
    p2 += __shfl_xor(p2, 16, 64);
    p2 += __shfl_xor(p2, 32, 64);   // now p2 = ||pred[nc]||^2 on every lane

    int psteps = (n_pos >> 4) / gridDim.y;          // 16-row tiles per y-slice
    int pbase  = blockIdx.y * psteps;

    float acc = 0.f;
    for (int ps = 0; ps < psteps; ++ps) {
        int p0 = (pbase + ps) << 4;
        const unsigned short* ta = tb + (size_t)(p0 + col) * DIMK + kb * 8;
        f32x4 d = {0.f, 0.f, 0.f, 0.f};
#pragma unroll
        for (int kk = 0; kk < 4; ++kk) {
            bf16x8 a = *(const bf16x8*)(ta + kk * 32);
            d = __builtin_amdgcn_mfma_f32_16x16x32_bf16(a, bfrag[kk], d, 0, 0, 0);
        }
        // this lane's 4 accumulator rows are p0 + kb*4 + {0..3}  (contiguous)
        const f32x4* twv = (const f32x4*)(tw + p0 + kb * 4);
        f32x4 w0 = twv[0];   // {t2[r0], w[r0], t2[r1], w[r1]}
        f32x4 w1 = twv[1];
        float t2v[4] = {w0[0], w0[2], w1[0], w1[2]};
        float wv[4]  = {w0[1], w0[3], w1[1], w1[3]};
#pragma unroll
        for (int j = 0; j < 4; ++j) {
            float sq = fmaf(-2.f, d[j], t2v[j] + p2);
            sq = fmaxf(sq, 0.f);
            float dist = __fsqrt_rn(sq + EPSQ);
            acc = fmaf(wv[j], dist, acc);
        }
    }
    // reduce the 4 lane-groups (lanes differing in bits 4..5) -> node total
    acc += __shfl_xor(acc, 16, 64);
    acc += __shfl_xor(acc, 32, 64);
    if (lane < 16 && n < n_nodes) atomicAdd(out + n, acc);
}

// ---- launcher --------------------------------------------------------------
extern "C" void kernel_launch(void* const* d_in, const int* in_sizes, int n_in,
                              void* d_out, int out_size, void* d_ws, size_t ws_size,
                              hipStream_t stream) {
    const float* pred  = (const float*)d_in[0];
    const float* tgt   = (const float*)d_in[1];
    const int*   ids   = (const int*)d_in[2];
    const int*   nsegp = (const int*)d_in[3];
    float* out = (float*)d_out;

    int n_nodes = in_sizes[0] / DIMK;
    int n_pos   = in_sizes[2];

    char* ws = (char*)d_ws;
    size_t off_tb = 0;
    size_t off_t2 = off_tb + (size_t)n_pos * DIMK * 2;   // bf16 target
    size_t off_tw = off_t2 + (size_t)n_pos * 4;          // t2
    unsigned short* tb = (unsigned short*)(ws + off_tb);
    float*          t2 = (float*)(ws + off_t2);
    float2*         tw = (float2*)(ws + off_tw);

    conv_target<<<(n_pos + 3) / 4, 256, 0, stream>>>(tgt, tb, t2, n_pos);
    seg_weights<<<1, 1024, 0, stream>>>(ids, nsegp, t2, tw, n_pos);
    hipMemsetAsync(out, 0, (size_t)out_size * sizeof(float), stream);

    dim3 grid((n_nodes + 63) / 64, 2);
    l2dist_main<<<grid, 256, 0, stream>>>(pred, tb, tw, out, n_nodes, n_pos);
}

// Round 2
// 149.806 us; speedup vs baseline: 1.6364x; 1.6364x over previous
//
#include <hip/hip_runtime.h>

#define DIMK 128
#define EPSQ 1e-8f

typedef __bf16 bf16x8 __attribute__((ext_vector_type(8)));
typedef float  f32x4  __attribute__((ext_vector_type(4)));

// ---- helpers ---------------------------------------------------------------
__device__ inline unsigned short f32_to_bf16_rne(float f) {
    unsigned u = __float_as_uint(f);
    u += 0x7FFFu + ((u >> 16) & 1u);      // round-to-nearest-even
    return (unsigned short)(u >> 16);
}

// ---- kernel 1: target f32 -> bf16, plus t2 = ||t||^2 -----------------------
__global__ void conv_target(const float* __restrict__ tgt,
                            unsigned short* __restrict__ tb,
                            float* __restrict__ t2, int n_pos) {
    int wave = threadIdx.x >> 6, lane = threadIdx.x & 63;
    int row = blockIdx.x * 4 + wave;
    if (row >= n_pos) return;
    float2 v = *(const float2*)(tgt + (size_t)row * DIMK + lane * 2);
    unsigned pk = (unsigned)f32_to_bf16_rne(v.x) |
                  ((unsigned)f32_to_bf16_rne(v.y) << 16);
    *(unsigned*)(tb + (size_t)row * DIMK + lane * 2) = pk;
    float s = v.x * v.x + v.y * v.y;
#pragma unroll
    for (int o = 1; o < 64; o <<= 1) s += __shfl_xor(s, o, 64);
    if (lane == 0) t2[row] = s;
}

// ---- kernel 2: segment counts -> per-position (t2, w) packed float2 --------
__global__ void seg_weights(const int* __restrict__ ids,
                            const int* __restrict__ nseg_p,
                            const float* __restrict__ t2,
                            float2* __restrict__ tw, int n_pos) {
    __shared__ int   cnt[256];
    __shared__ float w[256];
    int nseg = nseg_p[0];
    if (nseg > 256) nseg = 256;
    int t = threadIdx.x;
    if (t < nseg) cnt[t] = 0;
    __syncthreads();
    for (int p = t; p < n_pos; p += blockDim.x) atomicAdd(&cnt[ids[p]], 1);
    __syncthreads();
    if (t < nseg) w[t] = 1.0f / ((float)nseg * (float)max(cnt[t], 1));
    __syncthreads();
    for (int p = t; p < n_pos; p += blockDim.x) {
        float2 e; e.x = t2[p]; e.y = w[ids[p]];
        tw[p] = e;
    }
}

// ---- kernel 3: fused cross-GEMM + sqrt + weighted reduce -------------------
// block = 256 threads = 4 waves; wave owns 32 nodes (2 groups of 16);
// grid.y splits the 128 position-tiles.
__global__ __launch_bounds__(256)
void l2dist_main(const float* __restrict__ pred,
                 const unsigned short* __restrict__ tb,   // bf16 target bits
                 const float2* __restrict__ tw,
                 float* __restrict__ out,
                 int n_nodes, int n_pos) {
    int lane = threadIdx.x & 63;
    int wave = threadIdx.x >> 6;
    int col  = lane & 15;          // position row in A / node col in B
    int kb   = lane >> 4;          // k-block 0..3
    int n0   = blockIdx.x * 128 + wave * 32;

    // Build B fragments for both node groups (fp32 -> bf16 in registers) + p2.
    bf16x8 bfrag[2][4];
    float p2g[2];
#pragma unroll
    for (int g = 0; g < 2; ++g) {
        int n  = n0 + g * 16 + col;
        int nc = min(n, n_nodes - 1);
        const float* pr = pred + (size_t)nc * DIMK + kb * 8;
        float p2 = 0.f;
#pragma unroll
        for (int kk = 0; kk < 4; ++kk) {
            f32x4 f0 = *(const f32x4*)(pr + kk * 32);
            f32x4 f1 = *(const f32x4*)(pr + kk * 32 + 4);
            union { unsigned short s[8]; bf16x8 v; } u;
#pragma unroll
            for (int j = 0; j < 4; ++j) {
                u.s[j]     = f32_to_bf16_rne(f0[j]);
                u.s[4 + j] = f32_to_bf16_rne(f1[j]);
                p2 += f0[j] * f0[j] + f1[j] * f1[j];
            }
            bfrag[g][kk] = u.v;
        }
        p2 += __shfl_xor(p2, 16, 64);
        p2 += __shfl_xor(p2, 32, 64);   // full ||pred||^2 for this lane's col
        p2g[g] = p2;
    }

    int tiles = (n_pos >> 4) / gridDim.y;
    int pbase = blockIdx.y * tiles;

    float acc0 = 0.f, acc1 = 0.f;
#pragma unroll 2
    for (int ps = 0; ps < tiles; ++ps) {
        int p0 = (pbase + ps) << 4;
        const unsigned short* ta = tb + (size_t)(p0 + col) * DIMK + kb * 8;
        bf16x8 a[4];
#pragma unroll
        for (int kk = 0; kk < 4; ++kk) a[kk] = *(const bf16x8*)(ta + kk * 32);

        f32x4 d0 = {0.f, 0.f, 0.f, 0.f};
        f32x4 d1 = {0.f, 0.f, 0.f, 0.f};
#pragma unroll
        for (int kk = 0; kk < 4; ++kk) {
            d0 = __builtin_amdgcn_mfma_f32_16x16x32_bf16(a[kk], bfrag[0][kk], d0, 0, 0, 0);
            d1 = __builtin_amdgcn_mfma_f32_16x16x32_bf16(a[kk], bfrag[1][kk], d1, 0, 0, 0);
        }

        // this lane's 4 accumulator rows are p0 + kb*4 + {0..3}
        const f32x4* twv = (const f32x4*)(tw + p0 + kb * 4);
        f32x4 w0 = twv[0];   // {t2[r0], w[r0], t2[r1], w[r1]}
        f32x4 w1 = twv[1];
        float t2v[4] = {w0[0], w0[2], w1[0], w1[2]};
        float wv[4]  = {w0[1], w0[3], w1[1], w1[3]};
#pragma unroll
        for (int j = 0; j < 4; ++j) {
            float s0 = fmaf(-2.f, d0[j], t2v[j] + p2g[0]);
            float s1 = fmaf(-2.f, d1[j], t2v[j] + p2g[1]);
            s0 = fmaxf(s0, 0.f);
            s1 = fmaxf(s1, 0.f);
            acc0 = fmaf(wv[j], __builtin_amdgcn_sqrtf(s0 + EPSQ), acc0);
            acc1 = fmaf(wv[j], __builtin_amdgcn_sqrtf(s1 + EPSQ), acc1);
        }
    }
    // reduce over the 4 kb lane-groups -> per-node totals
    acc0 += __shfl_xor(acc0, 16, 64);
    acc0 += __shfl_xor(acc0, 32, 64);
    acc1 += __shfl_xor(acc1, 16, 64);
    acc1 += __shfl_xor(acc1, 32, 64);
    if (lane < 16) {
        int na = n0 + col;
        int nb = n0 + 16 + col;
        if (na < n_nodes) atomicAdd(out + na, acc0);
        if (nb < n_nodes) atomicAdd(out + nb, acc1);
    }
}

// ---- launcher --------------------------------------------------------------
extern "C" void kernel_launch(void* const* d_in, const int* in_sizes, int n_in,
                              void* d_out, int out_size, void* d_ws, size_t ws_size,
                              hipStream_t stream) {
    const float* pred  = (const float*)d_in[0];
    const float* tgt   = (const float*)d_in[1];
    const int*   ids   = (const int*)d_in[2];
    const int*   nsegp = (const int*)d_in[3];
    float* out = (float*)d_out;

    int n_nodes = in_sizes[0] / DIMK;
    int n_pos   = in_sizes[2];

    char* ws = (char*)d_ws;
    size_t off_tb = 0;
    size_t off_t2 = off_tb + (size_t)n_pos * DIMK * 2;   // bf16 target
    size_t off_tw = off_t2 + (size_t)n_pos * 4;          // t2
    unsigned short* tb = (unsigned short*)(ws + off_tb);
    float*          t2 = (float*)(ws + off_t2);
    float2*         tw = (float2*)(ws + off_tw);

    conv_target<<<(n_pos + 3) / 4, 256, 0, stream>>>(tgt, tb, t2, n_pos);
    seg_weights<<<1, 1024, 0, stream>>>(ids, nsegp, t2, tw, n_pos);
    hipMemsetAsync(out, 0, (size_t)out_size * sizeof(float), stream);

    dim3 grid((n_nodes + 127) / 128, 2);
    l2dist_main<<<grid, 256, 0, stream>>>(pred, tb, tw, out, n_nodes, n_pos);
}

// Round 3
// 76.072 us; speedup vs baseline: 3.2225x; 1.9693x over previous
//
#include <hip/hip_runtime.h>

#define DIMK 128

typedef __bf16 bf16x8 __attribute__((ext_vector_type(8)));
typedef float  f32x4  __attribute__((ext_vector_type(4)));

// ---- helpers ---------------------------------------------------------------
__device__ inline unsigned short f32_to_bf16_rne(float f) {
    unsigned u = __float_as_uint(f);
    u += 0x7FFFu + ((u >> 16) & 1u);      // round-to-nearest-even
    return (unsigned short)(u >> 16);
}

// ---- kernel 1: target f32 -> bf16 packed in MFMA-fragment tile order -------
// 16-position tile -> contiguous 4KB: ushort offset =
//   tile*2048 + kk*512 + (kb*16 + col)*8 + j   for element [tile*16+col][kk*32+kb*8+j]
__global__ void conv_target(const float* __restrict__ tgt,
                            unsigned short* __restrict__ tb,
                            float* __restrict__ t2, int n_pos) {
    int wave = threadIdx.x >> 6, lane = threadIdx.x & 63;
    int row = blockIdx.x * 4 + wave;
    if (row >= n_pos) return;
    int e = lane * 2;                       // element pair e, e+1
    float2 v = *(const float2*)(tgt + (size_t)row * DIMK + e);
    unsigned pk = (unsigned)f32_to_bf16_rne(v.x) |
                  ((unsigned)f32_to_bf16_rne(v.y) << 16);
    int tile = row >> 4, col = row & 15;
    int kk = e >> 5, kb = (e >> 3) & 3, j = e & 7;
    size_t dst = (size_t)tile * 2048 + kk * 512 + (kb * 16 + col) * 8 + j;
    *(unsigned*)(tb + dst) = pk;            // j even -> dword aligned
    float s = v.x * v.x + v.y * v.y;
#pragma unroll
    for (int o = 1; o < 64; o <<= 1) s += __shfl_xor(s, o, 64);
    if (lane == 0) t2[row] = s;
}

// ---- kernel 2: segment counts -> per-position (t2, w) packed float2 --------
__global__ void seg_weights(const int* __restrict__ ids,
                            const int* __restrict__ nseg_p,
                            const float* __restrict__ t2,
                            float2* __restrict__ tw, int n_pos) {
    __shared__ int   cnt[256];
    __shared__ float w[256];
    int nseg = nseg_p[0];
    if (nseg > 256) nseg = 256;
    int t = threadIdx.x;
    if (t < nseg) cnt[t] = 0;
    __syncthreads();
    for (int p = t; p < n_pos; p += blockDim.x) atomicAdd(&cnt[ids[p]], 1);
    __syncthreads();
    if (t < nseg) w[t] = 1.0f / ((float)nseg * (float)max(cnt[t], 1));
    __syncthreads();
    for (int p = t; p < n_pos; p += blockDim.x) {
        float2 e; e.x = t2[p]; e.y = w[ids[p]];
        tw[p] = e;
    }
}

// ---- tile compute: 8 MFMA + fused sqrt/weight epilogue ----------------------
__device__ __forceinline__ void tile_compute(
    const bf16x8 a[4], const bf16x8 b0[4], const bf16x8 b1[4],
    float p20, float p21, const float2* __restrict__ twt,
    float& acc0, float& acc1)
{
    f32x4 d0 = {0.f, 0.f, 0.f, 0.f};
    f32x4 d1 = {0.f, 0.f, 0.f, 0.f};
#pragma unroll
    for (int kk = 0; kk < 4; ++kk) {
        d0 = __builtin_amdgcn_mfma_f32_16x16x32_bf16(a[kk], b0[kk], d0, 0, 0, 0);
        d1 = __builtin_amdgcn_mfma_f32_16x16x32_bf16(a[kk], b1[kk], d1, 0, 0, 0);
    }
    f32x4 w0 = *(const f32x4*)(twt);        // {t2[r0], w[r0], t2[r1], w[r1]}
    f32x4 w1 = *(const f32x4*)(twt + 2);
    float t2v[4] = {w0[0], w0[2], w1[0], w1[2]};
    float wv[4]  = {w0[1], w0[3], w1[1], w1[3]};
#pragma unroll
    for (int j = 0; j < 4; ++j) {
        float s0 = fmaf(-2.f, d0[j], t2v[j] + p20);
        float s1 = fmaf(-2.f, d1[j], t2v[j] + p21);
        acc0 = fmaf(wv[j], __builtin_amdgcn_sqrtf(fmaxf(s0, 0.f)), acc0);
        acc1 = fmaf(wv[j], __builtin_amdgcn_sqrtf(fmaxf(s1, 0.f)), acc1);
    }
}

// ---- kernel 3: fused cross-GEMM + sqrt + weighted reduce -------------------
// 4 waves/block, wave owns 32 nodes; grid.y slices position-tiles;
// register double-buffer prefetch of the packed A-tiles.
__global__ __launch_bounds__(256)
void l2dist_main(const float* __restrict__ pred,
                 const unsigned short* __restrict__ tb,   // packed bf16 tiles
                 const float2* __restrict__ tw,
                 float* __restrict__ out,
                 int n_nodes, int tiles) {
    int lane = threadIdx.x & 63;
    int wave = threadIdx.x >> 6;
    int col  = lane & 15;
    int kb   = lane >> 4;
    int n0   = blockIdx.x * 128 + wave * 32;

    // B fragments for 2 node groups (fp32 -> bf16 in registers) + p2
    bf16x8 bfrag[2][4];
    float p2g[2];
#pragma unroll
    for (int g = 0; g < 2; ++g) {
        int n  = n0 + g * 16 + col;
        int nc = min(n, n_nodes - 1);
        const float* pr = pred + (size_t)nc * DIMK + kb * 8;
        float p2 = 0.f;
#pragma unroll
        for (int kk = 0; kk < 4; ++kk) {
            f32x4 f0 = *(const f32x4*)(pr + kk * 32);
            f32x4 f1 = *(const f32x4*)(pr + kk * 32 + 4);
            union { unsigned short s[8]; bf16x8 v; } u;
#pragma unroll
            for (int j = 0; j < 4; ++j) {
                u.s[j]     = f32_to_bf16_rne(f0[j]);
                u.s[4 + j] = f32_to_bf16_rne(f1[j]);
                p2 += f0[j] * f0[j] + f1[j] * f1[j];
            }
            bfrag[g][kk] = u.v;
        }
        p2 += __shfl_xor(p2, 16, 64);
        p2 += __shfl_xor(p2, 32, 64);
        p2g[g] = p2;
    }

    int pbase = blockIdx.y * tiles;         // first tile index of this slice
    const unsigned short* tp = tb + (size_t)pbase * 2048 + (size_t)lane * 8;
    const float2* twp = tw + ((size_t)pbase << 4) + kb * 4;

    float acc0 = 0.f, acc1 = 0.f;
    bf16x8 aA[4], aB[4];
#pragma unroll
    for (int kk = 0; kk < 4; ++kk) aA[kk] = *(const bf16x8*)(tp + kk * 512);

    for (int ps = 0; ps < tiles; ps += 2) {
        // prefetch tile ps+1 while computing ps
#pragma unroll
        for (int kk = 0; kk < 4; ++kk) aB[kk] = *(const bf16x8*)(tp + 2048 + kk * 512);
        tile_compute(aA, bfrag[0], bfrag[1], p2g[0], p2g[1], twp, acc0, acc1);
        // prefetch tile ps+2 while computing ps+1
        if (ps + 2 < tiles) {
#pragma unroll
            for (int kk = 0; kk < 4; ++kk) aA[kk] = *(const bf16x8*)(tp + 4096 + kk * 512);
        }
        tile_compute(aB, bfrag[0], bfrag[1], p2g[0], p2g[1], twp + 16, acc0, acc1);
        tp  += 4096;
        twp += 32;
    }

    // reduce over the 4 kb lane-groups -> per-node totals
    acc0 += __shfl_xor(acc0, 16, 64);
    acc0 += __shfl_xor(acc0, 32, 64);
    acc1 += __shfl_xor(acc1, 16, 64);
    acc1 += __shfl_xor(acc1, 32, 64);
    if (lane < 16) {
        int na = n0 + col;
        int nb = n0 + 16 + col;
        if (na < n_nodes) atomicAdd(out + na, acc0);
        if (nb < n_nodes) atomicAdd(out + nb, acc1);
    }
}

// ---- launcher --------------------------------------------------------------
extern "C" void kernel_launch(void* const* d_in, const int* in_sizes, int n_in,
                              void* d_out, int out_size, void* d_ws, size_t ws_size,
                              hipStream_t stream) {
    const float* pred  = (const float*)d_in[0];
    const float* tgt   = (const float*)d_in[1];
    const int*   ids   = (const int*)d_in[2];
    const int*   nsegp = (const int*)d_in[3];
    float* out = (float*)d_out;

    int n_nodes = in_sizes[0] / DIMK;
    int n_pos   = in_sizes[2];

    char* ws = (char*)d_ws;
    size_t off_tb = 0;
    size_t off_t2 = off_tb + (size_t)n_pos * DIMK * 2;   // packed bf16 target
    size_t off_tw = off_t2 + (size_t)n_pos * 4;          // t2
    unsigned short* tb = (unsigned short*)(ws + off_tb);
    float*          t2 = (float*)(ws + off_t2);
    float2*         tw = (float2*)(ws + off_tw);

    conv_target<<<(n_pos + 3) / 4, 256, 0, stream>>>(tgt, tb, t2, n_pos);
    seg_weights<<<1, 1024, 0, stream>>>(ids, nsegp, t2, tw, n_pos);
    hipMemsetAsync(out, 0, (size_t)out_size * sizeof(float), stream);

    const int YS = 8;                        // 128 tiles % 8 == 0
    int tiles = (n_pos >> 4) / YS;
    dim3 grid((n_nodes + 127) / 128, YS);
    l2dist_main<<<grid, 256, 0, stream>>>(pred, tb, tw, out, n_nodes, tiles);
}

// Round 4
// 65.757 us; speedup vs baseline: 3.7280x; 1.1569x over previous
//
#include <hip/hip_runtime.h>

#define DIMK 128

typedef __bf16 bf16x8 __attribute__((ext_vector_type(8)));
typedef float  f32x4  __attribute__((ext_vector_type(4)));

// ---- helpers ---------------------------------------------------------------
__device__ inline unsigned short f32_to_bf16_rne(float f) {
    unsigned u = __float_as_uint(f);
    u += 0x7FFFu + ((u >> 16) & 1u);      // round-to-nearest-even
    return (unsigned short)(u >> 16);
}

// Fragment-pack layout for a 16-row tile (rows = positions or nodes):
//   ushort offset = tile*2048 + kk*512 + (kb*16 + col)*8 + j
// for element [tile*16+col][kk*32 + kb*8 + j]. A and B fragments of
// mfma_f32_16x16x32_bf16 share this per-lane layout (lane = kb*16+col).

// ---- kernel 1: pack fp32 matrix -> bf16 fragment tiles + row norms ---------
// one wave per row; rows >= n_valid replicate the last valid row (padding).
__global__ void pack_rows(const float* __restrict__ src,
                          unsigned short* __restrict__ dst,
                          float* __restrict__ norm2,
                          int n_valid, int n_rows_pad) {
    int wave = threadIdx.x >> 6, lane = threadIdx.x & 63;
    int row = blockIdx.x * 4 + wave;
    if (row >= n_rows_pad) return;
    int srow = min(row, n_valid - 1);
    int e = lane * 2;
    float2 v = *(const float2*)(src + (size_t)srow * DIMK + e);
    unsigned pk = (unsigned)f32_to_bf16_rne(v.x) |
                  ((unsigned)f32_to_bf16_rne(v.y) << 16);
    int tile = row >> 4, col = row & 15;
    int kk = e >> 5, kb = (e >> 3) & 3, j = e & 7;
    size_t off = (size_t)tile * 2048 + kk * 512 + (kb * 16 + col) * 8 + j;
    *(unsigned*)(dst + off) = pk;           // j even -> dword aligned
    float s = v.x * v.x + v.y * v.y;
#pragma unroll
    for (int o = 1; o < 64; o <<= 1) s += __shfl_xor(s, o, 64);
    if (lane == 0) norm2[row] = s;
}

// ---- kernel 2: segment counts -> per-position (t2, w) packed float2 --------
__global__ void seg_weights(const int* __restrict__ ids,
                            const int* __restrict__ nseg_p,
                            const float* __restrict__ t2,
                            float2* __restrict__ tw, int n_pos) {
    __shared__ int   cnt[256];
    __shared__ float w[256];
    int nseg = nseg_p[0];
    if (nseg > 256) nseg = 256;
    int t = threadIdx.x;
    if (t < nseg) cnt[t] = 0;
    __syncthreads();
    for (int p = t; p < n_pos; p += blockDim.x) atomicAdd(&cnt[ids[p]], 1);
    __syncthreads();
    if (t < nseg) w[t] = 1.0f / ((float)nseg * (float)max(cnt[t], 1));
    __syncthreads();
    for (int p = t; p < n_pos; p += blockDim.x) {
        float2 e; e.x = t2[p]; e.y = w[ids[p]];
        tw[p] = e;
    }
}

// ---- tile compute: 8 MFMA + fused sqrt/weight epilogue ----------------------
__device__ __forceinline__ void tile_compute(
    const bf16x8 a[4], const bf16x8 b0[4], const bf16x8 b1[4],
    float p20, float p21, const float2* __restrict__ twt,
    float& acc0, float& acc1)
{
    f32x4 d0 = {0.f, 0.f, 0.f, 0.f};
    f32x4 d1 = {0.f, 0.f, 0.f, 0.f};
#pragma unroll
    for (int kk = 0; kk < 4; ++kk) {
        d0 = __builtin_amdgcn_mfma_f32_16x16x32_bf16(a[kk], b0[kk], d0, 0, 0, 0);
        d1 = __builtin_amdgcn_mfma_f32_16x16x32_bf16(a[kk], b1[kk], d1, 0, 0, 0);
    }
    f32x4 w0 = *(const f32x4*)(twt);        // {t2[r0], w[r0], t2[r1], w[r1]}
    f32x4 w1 = *(const f32x4*)(twt + 2);
    float t2v[4] = {w0[0], w0[2], w1[0], w1[2]};
    float wv[4]  = {w0[1], w0[3], w1[1], w1[3]};
#pragma unroll
    for (int j = 0; j < 4; ++j) {
        float s0 = fmaf(-2.f, d0[j], t2v[j] + p20);
        float s1 = fmaf(-2.f, d1[j], t2v[j] + p21);
        acc0 = fmaf(wv[j], __builtin_amdgcn_sqrtf(fmaxf(s0, 0.f)), acc0);
        acc1 = fmaf(wv[j], __builtin_amdgcn_sqrtf(fmaxf(s1, 0.f)), acc1);
    }
}

// ---- kernel 3: fused cross-GEMM + sqrt + weighted reduce -------------------
// 4 waves/block, wave owns 32 nodes (2 packed node-tiles, fragments from
// pre-packed bf16 pred); grid.y slices position-tiles; register dbuf on A.
__global__ __launch_bounds__(256)
void l2dist_main(const unsigned short* __restrict__ pb,   // packed bf16 pred
                 const float* __restrict__ p2,
                 const unsigned short* __restrict__ tb,   // packed bf16 target
                 const float2* __restrict__ tw,
                 float* __restrict__ out,
                 int n_nodes, int tiles) {
    int lane = threadIdx.x & 63;
    int wave = threadIdx.x >> 6;
    int col  = lane & 15;
    int kb   = lane >> 4;
    int n0   = blockIdx.x * 128 + wave * 32;

    // B fragments: two node-tiles, direct vector loads from packed pred.
    bf16x8 bfrag[2][4];
    float p2g[2];
    const unsigned short* bp = pb + ((size_t)(n0 >> 4)) * 2048 + (size_t)lane * 8;
#pragma unroll
    for (int g = 0; g < 2; ++g) {
#pragma unroll
        for (int kk = 0; kk < 4; ++kk)
            bfrag[g][kk] = *(const bf16x8*)(bp + g * 2048 + kk * 512);
        p2g[g] = p2[n0 + g * 16 + col];
    }

    int pbase = blockIdx.y * tiles;
    const unsigned short* tp = tb + (size_t)pbase * 2048 + (size_t)lane * 8;
    const float2* twp = tw + ((size_t)pbase << 4) + kb * 4;

    float acc0 = 0.f, acc1 = 0.f;
    bf16x8 aA[4], aB[4];
#pragma unroll
    for (int kk = 0; kk < 4; ++kk) aA[kk] = *(const bf16x8*)(tp + kk * 512);

    for (int ps = 0; ps < tiles; ps += 2) {
#pragma unroll
        for (int kk = 0; kk < 4; ++kk) aB[kk] = *(const bf16x8*)(tp + 2048 + kk * 512);
        tile_compute(aA, bfrag[0], bfrag[1], p2g[0], p2g[1], twp, acc0, acc1);
        if (ps + 2 < tiles) {
#pragma unroll
            for (int kk = 0; kk < 4; ++kk) aA[kk] = *(const bf16x8*)(tp + 4096 + kk * 512);
        }
        tile_compute(aB, bfrag[0], bfrag[1], p2g[0], p2g[1], twp + 16, acc0, acc1);
        tp  += 4096;
        twp += 32;
    }

    acc0 += __shfl_xor(acc0, 16, 64);
    acc0 += __shfl_xor(acc0, 32, 64);
    acc1 += __shfl_xor(acc1, 16, 64);
    acc1 += __shfl_xor(acc1, 32, 64);
    if (lane < 16) {
        int na = n0 + col;
        int nb = n0 + 16 + col;
        if (na < n_nodes) atomicAdd(out + na, acc0);
        if (nb < n_nodes) atomicAdd(out + nb, acc1);
    }
}

// ---- launcher --------------------------------------------------------------
extern "C" void kernel_launch(void* const* d_in, const int* in_sizes, int n_in,
                              void* d_out, int out_size, void* d_ws, size_t ws_size,
                              hipStream_t stream) {
    const float* pred  = (const float*)d_in[0];
    const float* tgt   = (const float*)d_in[1];
    const int*   ids   = (const int*)d_in[2];
    const int*   nsegp = (const int*)d_in[3];
    float* out = (float*)d_out;

    int n_nodes = in_sizes[0] / DIMK;
    int n_pos   = in_sizes[2];

    int gx = (n_nodes + 127) / 128;          // node blocks (128 nodes each)
    int n_rows_pad = gx * 128;               // pad pred tiles to grid coverage

    char* ws = (char*)d_ws;
    size_t off_pb = 0;                                        // packed pred bf16
    size_t off_tb = off_pb + (size_t)n_rows_pad * DIMK * 2;   // packed target bf16
    size_t off_p2 = off_tb + (size_t)n_pos * DIMK * 2;        // pred norms (padded)
    size_t off_t2 = off_p2 + (size_t)n_rows_pad * 4;          // target norms
    size_t off_tw = off_t2 + (size_t)n_pos * 4;               // (t2, w) pairs
    unsigned short* pb = (unsigned short*)(ws + off_pb);
    unsigned short* tb = (unsigned short*)(ws + off_tb);
    float*          p2 = (float*)(ws + off_p2);
    float*          t2 = (float*)(ws + off_t2);
    float2*         tw = (float2*)(ws + off_tw);

    pack_rows<<<(n_rows_pad + 3) / 4, 256, 0, stream>>>(pred, pb, p2, n_nodes, n_rows_pad);
    pack_rows<<<(n_pos + 3) / 4, 256, 0, stream>>>(tgt, tb, t2, n_pos, n_pos);
    seg_weights<<<1, 1024, 0, stream>>>(ids, nsegp, t2, tw, n_pos);
    hipMemsetAsync(out, 0, (size_t)out_size * sizeof(float), stream);

    const int YS = 8;                        // 128 position-tiles % 8 == 0
    int tiles = (n_pos >> 4) / YS;
    dim3 grid(gx, YS);
    l2dist_main<<<grid, 256, 0, stream>>>(pb, p2, tb, tw, out, n_nodes, tiles);
}

// Round 5
// 61.892 us; speedup vs baseline: 3.9609x; 1.0625x over previous
//
#include <hip/hip_runtime.h>

#define DIMK 128

typedef __bf16 bf16x8 __attribute__((ext_vector_type(8)));
typedef float  f32x4  __attribute__((ext_vector_type(4)));

// ---- helpers ---------------------------------------------------------------
__device__ inline unsigned short f32_to_bf16_rne(float f) {
    unsigned u = __float_as_uint(f);
    u += 0x7FFFu + ((u >> 16) & 1u);      // round-to-nearest-even
    return (unsigned short)(u >> 16);
}

// Fragment-pack layout for a 16-row tile:
//   ushort offset = tile*2048 + kk*512 + (kb*16 + col)*8 + j
// for element [tile*16+col][kk*32 + kb*8 + j]; per-lane (lane = kb*16+col)
// a fragment load is just  base + kk*512 + lane*8  -> 16B contiguous/lane.

// ---- kernel 1: pack fp32 matrix -> bf16 fragment tiles + row norms ---------
__global__ void pack_rows(const float* __restrict__ src,
                          unsigned short* __restrict__ dst,
                          float* __restrict__ norm2,
                          int n_valid, int n_rows_pad) {
    int wave = threadIdx.x >> 6, lane = threadIdx.x & 63;
    int row = blockIdx.x * 4 + wave;
    if (row >= n_rows_pad) return;
    int srow = min(row, n_valid - 1);
    int e = lane * 2;
    float2 v = *(const float2*)(src + (size_t)srow * DIMK + e);
    unsigned pk = (unsigned)f32_to_bf16_rne(v.x) |
                  ((unsigned)f32_to_bf16_rne(v.y) << 16);
    int tile = row >> 4, col = row & 15;
    int kk = e >> 5, kb = (e >> 3) & 3, j = e & 7;
    size_t off = (size_t)tile * 2048 + kk * 512 + (kb * 16 + col) * 8 + j;
    *(unsigned*)(dst + off) = pk;           // j even -> dword aligned
    float s = v.x * v.x + v.y * v.y;
#pragma unroll
    for (int o = 1; o < 64; o <<= 1) s += __shfl_xor(s, o, 64);
    if (lane == 0) norm2[row] = s;
}

// ---- kernel 2: segment counts -> per-position (t2, w) packed float2 --------
__global__ void seg_weights(const int* __restrict__ ids,
                            const int* __restrict__ nseg_p,
                            const float* __restrict__ t2,
                            float2* __restrict__ tw, int n_pos) {
    __shared__ int   cnt[256];
    __shared__ float w[256];
    int nseg = nseg_p[0];
    if (nseg > 256) nseg = 256;
    int t = threadIdx.x;
    if (t < nseg) cnt[t] = 0;
    __syncthreads();
    for (int p = t; p < n_pos; p += blockDim.x) atomicAdd(&cnt[ids[p]], 1);
    __syncthreads();
    if (t < nseg) w[t] = 1.0f / ((float)nseg * (float)max(cnt[t], 1));
    __syncthreads();
    for (int p = t; p < n_pos; p += blockDim.x) {
        float2 e; e.x = t2[p]; e.y = w[ids[p]];
        tw[p] = e;
    }
}

// ---- kernel 3: fused cross-GEMM + sqrt + weighted reduce -------------------
// 4 waves/block; wave owns 32 nodes (128/block). Target tiles are staged
// into LDS once per block (global_load_lds width=16, linear layout,
// double-buffered, one barrier per tile). tw prefetched 1 tile ahead.
__global__ __launch_bounds__(256)
void l2dist_main(const unsigned short* __restrict__ pb,   // packed bf16 pred
                 const float* __restrict__ p2,
                 const unsigned short* __restrict__ tb,   // packed bf16 target
                 const float2* __restrict__ tw,
                 float* __restrict__ out,
                 int n_nodes, int tiles) {
    __shared__ __align__(16) unsigned short lbuf[2][2048];   // 2 x 4KB tiles
    const int lane = threadIdx.x & 63;
    const int wave = threadIdx.x >> 6;
    const int col  = lane & 15;
    const int kb   = lane >> 4;
    const int n0   = blockIdx.x * 128 + wave * 32;

    // B fragments: two node-tiles from packed pred + norms.
    bf16x8 bfrag[2][4];
    float p2g[2];
    const unsigned short* bp = pb + ((size_t)(n0 >> 4)) * 2048 + (size_t)lane * 8;
#pragma unroll
    for (int g = 0; g < 2; ++g) {
#pragma unroll
        for (int kk = 0; kk < 4; ++kk)
            bfrag[g][kk] = *(const bf16x8*)(bp + g * 2048 + kk * 512);
        p2g[g] = p2[n0 + g * 16 + col];
    }

    const int pbase = blockIdx.y * tiles;
    // each wave stages its own 1KB quarter of the 4KB tile (linear in lane)
    const unsigned short* sp = tb + (size_t)pbase * 2048 + wave * 512 + lane * 8;
    unsigned short* ld0 = &lbuf[0][wave * 512];
    unsigned short* ld1 = &lbuf[1][wave * 512];
    const float2* twp = tw + ((size_t)pbase << 4) + kb * 4;

    // prologue: stage tile 0 into buf 0; preload tw(0)
    __builtin_amdgcn_global_load_lds(
        (const __attribute__((address_space(1))) unsigned int*)(const void*)sp,
        (__attribute__((address_space(3))) unsigned int*)(void*)ld0, 16, 0, 0);
    sp += 2048;
    f32x4 cw0 = *(const f32x4*)(twp);
    f32x4 cw1 = *(const f32x4*)(twp + 2);
    twp += 16;

    float acc0 = 0.f, acc1 = 0.f;

    for (int t = 0; t < tiles; ++t) {
        // barrier drains vmcnt(0) (stage(t) landed in LDS for every wave) and
        // orders all waves' reads of the other buffer before we overwrite it.
        asm volatile("s_waitcnt vmcnt(0)" ::: "memory");
        __syncthreads();

        if (t + 1 < tiles) {
            __builtin_amdgcn_global_load_lds(
                (const __attribute__((address_space(1))) unsigned int*)(const void*)sp,
                (__attribute__((address_space(3))) unsigned int*)(void*)((t & 1) ? ld0 : ld1),
                16, 0, 0);
            sp += 2048;
        }
        f32x4 nw0 = cw0, nw1 = cw1;
        if (t + 1 < tiles) {
            nw0 = *(const f32x4*)(twp);
            nw1 = *(const f32x4*)(twp + 2);
            twp += 16;
        }

        const unsigned short* rb = &lbuf[t & 1][lane * 8];
        bf16x8 a0 = *(const bf16x8*)(rb);
        bf16x8 a1 = *(const bf16x8*)(rb + 512);
        bf16x8 a2 = *(const bf16x8*)(rb + 1024);
        bf16x8 a3 = *(const bf16x8*)(rb + 1536);

        f32x4 d0 = {0.f, 0.f, 0.f, 0.f};
        f32x4 d1 = {0.f, 0.f, 0.f, 0.f};
        d0 = __builtin_amdgcn_mfma_f32_16x16x32_bf16(a0, bfrag[0][0], d0, 0, 0, 0);
        d1 = __builtin_amdgcn_mfma_f32_16x16x32_bf16(a0, bfrag[1][0], d1, 0, 0, 0);
        d0 = __builtin_amdgcn_mfma_f32_16x16x32_bf16(a1, bfrag[0][1], d0, 0, 0, 0);
        d1 = __builtin_amdgcn_mfma_f32_16x16x32_bf16(a1, bfrag[1][1], d1, 0, 0, 0);
        d0 = __builtin_amdgcn_mfma_f32_16x16x32_bf16(a2, bfrag[0][2], d0, 0, 0, 0);
        d1 = __builtin_amdgcn_mfma_f32_16x16x32_bf16(a2, bfrag[1][2], d1, 0, 0, 0);
        d0 = __builtin_amdgcn_mfma_f32_16x16x32_bf16(a3, bfrag[0][3], d0, 0, 0, 0);
        d1 = __builtin_amdgcn_mfma_f32_16x16x32_bf16(a3, bfrag[1][3], d1, 0, 0, 0);

        float t2v[4] = {cw0[0], cw0[2], cw1[0], cw1[2]};
        float wv[4]  = {cw0[1], cw0[3], cw1[1], cw1[3]};
#pragma unroll
        for (int j = 0; j < 4; ++j) {
            float s0 = fmaf(-2.f, d0[j], t2v[j] + p2g[0]);
            float s1 = fmaf(-2.f, d1[j], t2v[j] + p2g[1]);
            acc0 = fmaf(wv[j], __builtin_amdgcn_sqrtf(fmaxf(s0, 0.f)), acc0);
            acc1 = fmaf(wv[j], __builtin_amdgcn_sqrtf(fmaxf(s1, 0.f)), acc1);
        }
        cw0 = nw0; cw1 = nw1;
    }

    // reduce over the 4 kb lane-groups -> per-node totals
    acc0 += __shfl_xor(acc0, 16, 64);
    acc0 += __shfl_xor(acc0, 32, 64);
    acc1 += __shfl_xor(acc1, 16, 64);
    acc1 += __shfl_xor(acc1, 32, 64);
    if (lane < 16) {
        int na = n0 + col;
        int nb = n0 + 16 + col;
        if (na < n_nodes) atomicAdd(out + na, acc0);
        if (nb < n_nodes) atomicAdd(out + nb, acc1);
    }
}

// ---- launcher --------------------------------------------------------------
extern "C" void kernel_launch(void* const* d_in, const int* in_sizes, int n_in,
                              void* d_out, int out_size, void* d_ws, size_t ws_size,
                              hipStream_t stream) {
    const float* pred  = (const float*)d_in[0];
    const float* tgt   = (const float*)d_in[1];
    const int*   ids   = (const int*)d_in[2];
    const int*   nsegp = (const int*)d_in[3];
    float* out = (float*)d_out;

    int n_nodes = in_sizes[0] / DIMK;
    int n_pos   = in_sizes[2];

    int gx = (n_nodes + 127) / 128;          // node blocks (128 nodes each)
    int n_rows_pad = gx * 128;               // pad pred tiles to grid coverage

    char* ws = (char*)d_ws;
    size_t off_pb = 0;                                        // packed pred bf16
    size_t off_tb = off_pb + (size_t)n_rows_pad * DIMK * 2;   // packed target bf16
    size_t off_p2 = off_tb + (size_t)n_pos * DIMK * 2;        // pred norms (padded)
    size_t off_t2 = off_p2 + (size_t)n_rows_pad * 4;          // target norms
    size_t off_tw = off_t2 + (size_t)n_pos * 4;               // (t2, w) pairs
    unsigned short* pb = (unsigned short*)(ws + off_pb);
    unsigned short* tb = (unsigned short*)(ws + off_tb);
    float*          p2 = (float*)(ws + off_p2);
    float*          t2 = (float*)(ws + off_t2);
    float2*         tw = (float2*)(ws + off_tw);

    pack_rows<<<(n_rows_pad + 3) / 4, 256, 0, stream>>>(pred, pb, p2, n_nodes, n_rows_pad);
    pack_rows<<<(n_pos + 3) / 4, 256, 0, stream>>>(tgt, tb, t2, n_pos, n_pos);
    seg_weights<<<1, 1024, 0, stream>>>(ids, nsegp, t2, tw, n_pos);
    hipMemsetAsync(out, 0, (size_t)out_size * sizeof(float), stream);

    const int YS = 8;                        // 128 position-tiles % 8 == 0
    int tiles = (n_pos >> 4) / YS;
    dim3 grid(gx, YS);
    l2dist_main<<<grid, 256, 0, stream>>>(pb, p2, tb, tw, out, n_nodes, tiles);
}